// Round 11
// baseline (399.079 us; speedup 1.0000x reference)
//
#include <hip/hip_runtime.h>
#include <hip/hip_fp8.h>
#include <cstddef>
#include <cstdint>

#define N_NODES 50000
#define N_EDGES 800000
#define D 128
#define NWG 128                            // binning slices
#define EPW (N_EDGES / NWG)                // 6250 edges per slice
#define NBUCK 196                          // ceil(50000/256)
#define NBLK 512                           // fused_prep grid (2/CU co-resident)
#define FCONV_TOTAL 3125                   // N*D/8/256 exactly
#define FCONV_P1 1904                      // phase-1 share (128+16+1904 = 2048)
#define FCONV_P2 (FCONV_TOTAL - FCONV_P1)  // 1221 in phase 2
#define WSPLIT_BLKS 16

typedef __attribute__((ext_vector_type(8))) short bf16x8;
typedef __attribute__((ext_vector_type(16))) float f32x16;
typedef __attribute__((ext_vector_type(2))) float f32x2;

__device__ __forceinline__ unsigned short f32_to_bf16_rne(float x) {
    unsigned u = __builtin_bit_cast(unsigned, x);
    unsigned r = (u + 0x7FFFu + ((u >> 16) & 1u)) >> 16;
    return (unsigned short)r;
}

// ---- fp8 e4m3 pack/unpack (HW cvt on gfx950; hip_fp8 fallback) ----
#if __has_builtin(__builtin_amdgcn_cvt_pk_fp8_f32) && __has_builtin(__builtin_amdgcn_cvt_pk_f32_fp8)
__device__ __forceinline__ unsigned fp8x4_pack(float v0, float v1, float v2, float v3) {
    int w = 0;
    w = __builtin_amdgcn_cvt_pk_fp8_f32(v0, v1, w, false);   // bytes 0,1
    w = __builtin_amdgcn_cvt_pk_fp8_f32(v2, v3, w, true);    // bytes 2,3
    return (unsigned)w;
}
__device__ __forceinline__ f32x2 fp8x2_lo(unsigned u) {
    return __builtin_amdgcn_cvt_pk_f32_fp8((int)u, false);
}
__device__ __forceinline__ f32x2 fp8x2_hi(unsigned u) {
    return __builtin_amdgcn_cvt_pk_f32_fp8((int)u, true);
}
#else
__device__ __forceinline__ unsigned fp8x4_pack(float v0, float v1, float v2, float v3) {
    __hip_fp8_e4m3 a(v0), b(v1), c(v2), d(v3);
    return (unsigned)a.__x | ((unsigned)b.__x << 8) | ((unsigned)c.__x << 16) | ((unsigned)d.__x << 24);
}
__device__ __forceinline__ float fp8_dec(unsigned byte) {
    __hip_fp8_e4m3 h; h.__x = (__hip_fp8_storage_t)byte;
    return (float)h;
}
__device__ __forceinline__ f32x2 fp8x2_lo(unsigned u) {
    f32x2 r; r.x = fp8_dec(u & 255u); r.y = fp8_dec((u >> 8) & 255u); return r;
}
__device__ __forceinline__ f32x2 fp8x2_hi(unsigned u) {
    f32x2 r; r.x = fp8_dec((u >> 16) & 255u); r.y = fp8_dec(u >> 24); return r;
}
#endif

// ---------------- barrier state init (ws is poisoned 0xAA before timing) ----------------
__global__ void init_bars_kernel(unsigned* __restrict__ bars) {
    if (threadIdx.x < 4) bars[threadIdx.x] = 0u;
}

// ---------------- software grid barrier: monotonic counter, co-resident grid ----------------
__device__ __forceinline__ void grid_barrier(unsigned* cnt) {
    __syncthreads();
    if (threadIdx.x == 0) {
        __threadfence();                                       // device-scope release of prior writes
        __hip_atomic_fetch_add(cnt, 1u, __ATOMIC_ACQ_REL, __HIP_MEMORY_SCOPE_AGENT);
        int spins = 0;
        while (__hip_atomic_load(cnt, __ATOMIC_ACQUIRE, __HIP_MEMORY_SCOPE_AGENT) < NBLK) {
            __builtin_amdgcn_s_sleep(4);
            if (++spins > (1 << 22)) break;                    // failsafe: fail, don't hang
        }
    }
    __syncthreads();
}

// ---------------- fused prep: {s1|wsplit|fconv} -> bar -> {s3|fconv} -> bar -> finalize ----------------
__global__ void __launch_bounds__(256, 2) fused_prep(
    const float* __restrict__ feat,
    const float* __restrict__ Wself,
    const float* __restrict__ Wneigh,
    const int* __restrict__ src,
    const int* __restrict__ dst,
    unsigned short* __restrict__ featb,
    unsigned char* __restrict__ feat8,
    unsigned short* __restrict__ Wf,
    int* __restrict__ ghist,
    unsigned* __restrict__ binned,
    int* __restrict__ gboff,
    int* __restrict__ deg_i,
    int* __restrict__ off,
    unsigned short* __restrict__ csr_src,
    unsigned* __restrict__ bars)
{
    __shared__ int sm0[256];
    __shared__ int sm1[256];
    __shared__ int sm2[256];
    const int t = threadIdx.x;
    const int bid = blockIdx.x;

    // ========== phase 1: s1 hist (vb 0..127) | wsplit (128..143) | fconvA ==========
    for (int vb = bid; vb < 2048; vb += NBLK) {
        if (vb < NWG) {
            sm0[t] = 0;
            __syncthreads();
            const int base = vb * EPW;
            for (int i = t; i < EPW; i += 256)
                atomicAdd(&sm0[dst[base + i] >> 8], 1);
            __syncthreads();
            ghist[vb * 256 + t] = sm0[t];
        } else if (vb < NWG + WSPLIT_BLKS) {
            const int unit = (vb - NWG) * 256 + t;   // 0..4095 exact
            const int phase = unit >> 11;
            const int kbi   = (unit >> 9) & 3;
            const int u     = unit & 511;
            const int j     = u & 127;
            const int c     = u >> 7;
            const float* __restrict__ W = phase ? Wneigh : Wself;
            const float* gp = &W[(size_t)j * D + kbi * 32 + c * 8];
            const int p = j >> 5, ks = c >> 1, g = c & 1;
            const size_t base = (size_t)(phase * 4 + kbi) * 4096
                              + (size_t)(((p * 2 + ks) * 64) + (j & 31) + 32 * g) * 8;
#pragma unroll
            for (int e = 0; e < 8; ++e)
                Wf[base + e] = f32_to_bf16_rne(gp[e]);
        } else {
            const int i = (vb - NWG - WSPLIT_BLKS) * 256 + t;   // 0..1903 vblocks
            const float* gp = feat + (size_t)i * 8;
            const float4 a = *(const float4*)gp;
            const float4 b = *(const float4*)(gp + 4);
            bf16x8 h;
            h[0] = (short)f32_to_bf16_rne(a.x); h[1] = (short)f32_to_bf16_rne(a.y);
            h[2] = (short)f32_to_bf16_rne(a.z); h[3] = (short)f32_to_bf16_rne(a.w);
            h[4] = (short)f32_to_bf16_rne(b.x); h[5] = (short)f32_to_bf16_rne(b.y);
            h[6] = (short)f32_to_bf16_rne(b.z); h[7] = (short)f32_to_bf16_rne(b.w);
            *(bf16x8*)&featb[(size_t)i * 8] = h;
            uint2 q;
            q.x = fp8x4_pack(a.x, a.y, a.z, a.w);
            q.y = fp8x4_pack(b.x, b.y, b.z, b.w);
            *(uint2*)&feat8[(size_t)i * 8] = q;
        }
    }
    grid_barrier(&bars[0]);

    // ========== phase 2: s3 binning (vb 0..127) | fconvB ==========
    for (int vb = bid; vb < NWG + FCONV_P2; vb += NBLK) {
        if (vb < NWG) {
            int tot = 0, mypre = 0;
            for (int w2 = 0; w2 < NWG; ++w2) {
                const int v = ghist[w2 * 256 + t];
                tot += v;
                if (w2 < vb) mypre += v;
            }
            sm0[t] = tot;
            __syncthreads();
            for (int d = 1; d < 256; d <<= 1) {
                int v = 0;
                if (t >= d) v = sm0[t - d];
                __syncthreads();
                sm0[t] += v;
                __syncthreads();
            }
            const int boff = sm0[t] - tot;   // exclusive bucket offset
            if (vb == 0) {
                gboff[t] = boff;
                if (t == 255) gboff[256] = sm0[255];
            }
            sm1[t] = boff + mypre;
            __syncthreads();
            const int base = vb * EPW;
            for (int i = t; i < EPW; i += 256) {
                const int sv = src[base + i];
                const int d = dst[base + i];
                const int p = atomicAdd(&sm1[d >> 8], 1);
                binned[p] = (unsigned)sv | ((unsigned)(d & 255) << 16);
            }
            __syncthreads();   // sm0/sm1 quiescent before any later reuse
        } else {
            const int i = (FCONV_P1 + vb - NWG) * 256 + t;   // 1904..3124 vblocks
            const float* gp = feat + (size_t)i * 8;
            const float4 a = *(const float4*)gp;
            const float4 b = *(const float4*)(gp + 4);
            bf16x8 h;
            h[0] = (short)f32_to_bf16_rne(a.x); h[1] = (short)f32_to_bf16_rne(a.y);
            h[2] = (short)f32_to_bf16_rne(a.z); h[3] = (short)f32_to_bf16_rne(a.w);
            h[4] = (short)f32_to_bf16_rne(b.x); h[5] = (short)f32_to_bf16_rne(b.y);
            h[6] = (short)f32_to_bf16_rne(b.z); h[7] = (short)f32_to_bf16_rne(b.w);
            *(bf16x8*)&featb[(size_t)i * 8] = h;
            uint2 q;
            q.x = fp8x4_pack(a.x, a.y, a.z, a.w);
            q.y = fp8x4_pack(b.x, b.y, b.z, b.w);
            *(uint2*)&feat8[(size_t)i * 8] = q;
        }
    }
    grid_barrier(&bars[1]);

    // ========== phase 3: finalize (vb 0..195) ==========
    for (int vb = bid; vb < NBUCK; vb += NBLK) {
        sm0[t] = 0;
        __syncthreads();
        const int lo = gboff[vb], hi = gboff[vb + 1];
        for (int i = lo + t; i < hi; i += 256)
            atomicAdd(&sm0[(binned[i] >> 16) & 255u], 1);
        __syncthreads();
        const int c = sm0[t];
        sm1[t] = c;
        __syncthreads();
        for (int d = 1; d < 256; d <<= 1) {
            int v = 0;
            if (t >= d) v = sm1[t - d];
            __syncthreads();
            sm1[t] += v;
            __syncthreads();
        }
        const int o = gboff[vb] + sm1[t] - c;   // global CSR offset for this node
        const int node = vb * 256 + t;
        if (node < N_NODES) {
            deg_i[node] = c;
            off[node] = o;
        }
        sm2[t] = o;
        __syncthreads();
        for (int i = lo + t; i < hi; i += 256) {
            const unsigned u = binned[i];
            const int p = atomicAdd(&sm2[(u >> 16) & 255u], 1);
            csr_src[p] = (unsigned short)(u & 0xFFFFu);
        }
        __syncthreads();
    }
}

// ---------------- gather-aggregate: fp8 rows, 16 lanes/row, unroll 8, bf16 out ----------------
__launch_bounds__(256)
__global__ void gather_kernel(const unsigned char* __restrict__ feat8,
                              const int* __restrict__ off,
                              const int* __restrict__ deg_i,
                              const unsigned short* __restrict__ csr_src,
                              unsigned short* __restrict__ hneighb) {
    const int t = threadIdx.x;
    const int lane8 = (t & 15) * 8;                 // byte/feature base: 8 fp8 per lane
    const int node = blockIdx.x * 16 + (t >> 4);    // 16 nodes per 256-thread block
    if (node >= N_NODES) return;
    const int s0 = off[node];
    const int cnt = deg_i[node];
    const int end = s0 + cnt;
    float a0 = 0.f, a1 = 0.f, a2 = 0.f, a3 = 0.f;
    float a4 = 0.f, a5 = 0.f, a6 = 0.f, a7 = 0.f;
    int e = s0;
#define ACC(u) { const f32x2 p0 = fp8x2_lo((u).x); const f32x2 p1 = fp8x2_hi((u).x); \
                 const f32x2 p2 = fp8x2_lo((u).y); const f32x2 p3 = fp8x2_hi((u).y); \
                 a0 += p0.x; a1 += p0.y; a2 += p1.x; a3 += p1.y; \
                 a4 += p2.x; a5 += p2.y; a6 += p3.x; a7 += p3.y; }
    for (; e + 8 <= end; e += 8) {
        const int i0 = csr_src[e];
        const int i1 = csr_src[e + 1];
        const int i2 = csr_src[e + 2];
        const int i3 = csr_src[e + 3];
        const int i4 = csr_src[e + 4];
        const int i5 = csr_src[e + 5];
        const int i6 = csr_src[e + 6];
        const int i7 = csr_src[e + 7];
        const uint2 u0 = *(const uint2*)&feat8[(size_t)i0 * D + lane8];
        const uint2 u1 = *(const uint2*)&feat8[(size_t)i1 * D + lane8];
        const uint2 u2 = *(const uint2*)&feat8[(size_t)i2 * D + lane8];
        const uint2 u3 = *(const uint2*)&feat8[(size_t)i3 * D + lane8];
        const uint2 u4 = *(const uint2*)&feat8[(size_t)i4 * D + lane8];
        const uint2 u5 = *(const uint2*)&feat8[(size_t)i5 * D + lane8];
        const uint2 u6 = *(const uint2*)&feat8[(size_t)i6 * D + lane8];
        const uint2 u7 = *(const uint2*)&feat8[(size_t)i7 * D + lane8];
        ACC(u0); ACC(u1); ACC(u2); ACC(u3);
        ACC(u4); ACC(u5); ACC(u6); ACC(u7);
    }
    for (; e + 4 <= end; e += 4) {
        const int i0 = csr_src[e];
        const int i1 = csr_src[e + 1];
        const int i2 = csr_src[e + 2];
        const int i3 = csr_src[e + 3];
        const uint2 u0 = *(const uint2*)&feat8[(size_t)i0 * D + lane8];
        const uint2 u1 = *(const uint2*)&feat8[(size_t)i1 * D + lane8];
        const uint2 u2 = *(const uint2*)&feat8[(size_t)i2 * D + lane8];
        const uint2 u3 = *(const uint2*)&feat8[(size_t)i3 * D + lane8];
        ACC(u0); ACC(u1); ACC(u2); ACC(u3);
    }
    for (; e < end; ++e) {
        const uint2 u = *(const uint2*)&feat8[(size_t)csr_src[e] * D + lane8];
        ACC(u);
    }
#undef ACC
    const float sc = 1.f / fmaxf((float)cnt, 1.f);
    const unsigned h0 = f32_to_bf16_rne(a0 * sc);
    const unsigned h1 = f32_to_bf16_rne(a1 * sc);
    const unsigned h2 = f32_to_bf16_rne(a2 * sc);
    const unsigned h3 = f32_to_bf16_rne(a3 * sc);
    const unsigned h4 = f32_to_bf16_rne(a4 * sc);
    const unsigned h5 = f32_to_bf16_rne(a5 * sc);
    const unsigned h6 = f32_to_bf16_rne(a6 * sc);
    const unsigned h7 = f32_to_bf16_rne(a7 * sc);
    uint4 o;
    o.x = (h1 << 16) | h0;
    o.y = (h3 << 16) | h2;
    o.z = (h5 << 16) | h4;
    o.w = (h7 << 16) | h6;
    *(uint4*)&hneighb[(size_t)node * D + lane8] = o;
}

// ---------------- MFMA GEMM, pure bf16, W resident in LDS ----------------
__launch_bounds__(256)
__global__ void gemm_kernel(const unsigned short* __restrict__ featb,
                            const unsigned short* __restrict__ hneighb,
                            const unsigned short* __restrict__ Wf,
                            const float* __restrict__ bias,
                            float* __restrict__ out) {
    __shared__ __align__(16) unsigned short sW[32768];      // 64 KB: all 8 W chunks
    __shared__ __align__(16) unsigned short sA[2][4096];    // 2 x 8 KB A tiles

    const int tid  = threadIdx.x;
    const int wv   = tid >> 6;   // wave 0..3 -> A panel (rows wv*32..wv*32+31)
    const int l    = tid & 63;
    const int row0 = blockIdx.x * 128;

    // ---- load ALL of W once (64 KB, contiguous) ----
#pragma unroll
    for (int i = 0; i < 16; ++i) {
        const int o = (i * 256 + tid) * 8;
        *(bf16x8*)&sW[o] = *(const bf16x8*)&Wf[o];
    }

    auto stageA = [&](int sel, int blk) {
        const int kbi = blk & 3;
        const unsigned short* __restrict__ A = (blk < 4) ? featb : hneighb;
#pragma unroll
        for (int i = 0; i < 2; ++i) {
            const int u   = i * 256 + tid;   // 0..511 = 128 rows x 4 chunks
            const int row = u & 127;
            const int c   = u >> 7;          // 8-k chunk within the 32-k block
            const int grow = row0 + row;
            bf16x8 v = {};
            if (grow < N_NODES)
                v = *(const bf16x8*)&A[(size_t)grow * D + kbi * 32 + c * 8];
            const int p = row >> 5, ks = c >> 1, g = c & 1;
            const int o = ((p * 2 + ks) * 64 + (row & 31) + 32 * g) * 8;
            *(bf16x8*)&sA[sel][o] = v;
        }
    };

    f32x16 acc[4] = {};

    stageA(0, 0);
    __syncthreads();
#pragma unroll 1
    for (int blk = 0; blk < 8; ++blk) {
        const int cur = blk & 1;
        if (blk < 7) stageA(cur ^ 1, blk + 1);
        const int wbase = blk * 4096;
#pragma unroll
        for (int ks = 0; ks < 2; ++ks) {
            const bf16x8 a = *(const bf16x8*)&sA[cur][((wv * 2 + ks) * 64 + l) * 8];
#pragma unroll
            for (int n = 0; n < 4; ++n) {
                const bf16x8 w = *(const bf16x8*)&sW[wbase + ((n * 2 + ks) * 64 + l) * 8];
                acc[n] = __builtin_amdgcn_mfma_f32_32x32x16_bf16(a, w, acc[n], 0, 0, 0);
            }
        }
        __syncthreads();
    }

    // ---- epilogue: C/D layout col=l&31, row=(r&3)+8*(r>>2)+4*(l>>5) ----
    const int col = l & 31;
    const int hi2 = l >> 5;
    float bv[4];
#pragma unroll
    for (int n = 0; n < 4; ++n) bv[n] = bias[n * 32 + col];
#pragma unroll
    for (int r = 0; r < 16; ++r) {
        const int rloc = (r & 3) + 8 * (r >> 2) + 4 * hi2;
        const int grow = row0 + wv * 32 + rloc;
        if (grow < N_NODES) {
#pragma unroll
            for (int n = 0; n < 4; ++n)
                out[(size_t)grow * D + n * 32 + col] = acc[n][r] + bv[n];
        }
    }
}

extern "C" void kernel_launch(void* const* d_in, const int* in_sizes, int n_in,
                              void* d_out, int out_size, void* d_ws, size_t ws_size,
                              hipStream_t stream) {
    const float* feat  = (const float*)d_in[0];
    const float* Wn    = (const float*)d_in[1];  // W_neigh
    const float* Wsf   = (const float*)d_in[2];  // W_self
    const float* bself = (const float*)d_in[3];
    const int*   src   = (const int*)d_in[4];
    const int*   dst   = (const int*)d_in[5];
    float* out = (float*)d_out;

    // workspace layout (all sections keep 16B alignment)
    unsigned short* featb   = (unsigned short*)d_ws;               // N*D bf16
    unsigned short* hneighb = featb + (size_t)N_NODES * D;         // N*D bf16
    unsigned* binned = (unsigned*)(hneighb + (size_t)N_NODES * D); // E uint (packed)
    unsigned short* csr_src = (unsigned short*)(binned + N_EDGES); // E ushort
    int*   deg_i     = (int*)(csr_src + N_EDGES);                  // N ints
    int*   off       = deg_i + N_NODES;                            // N ints
    int*   ghist     = off + N_NODES;                              // NWG*256 ints
    int*   gboff     = ghist + NWG * 256;                          // 257 ints (pad 320)
    unsigned short* Wf = (unsigned short*)(gboff + 320);           // 8*4096 bf16
    unsigned char* feat8 = (unsigned char*)(Wf + 8 * 4096);        // N*D fp8
    unsigned* bars = (unsigned*)(feat8 + (size_t)N_NODES * D);     // 4 uints

    init_bars_kernel<<<1, 64, 0, stream>>>(bars);
    fused_prep<<<NBLK, 256, 0, stream>>>(
        feat, Wsf, Wn, src, dst, featb, feat8, Wf,
        ghist, binned, gboff, deg_i, off, csr_src, bars);
    gather_kernel<<<(N_NODES + 15) / 16, 256, 0, stream>>>(feat8, off, deg_i, csr_src, hneighb);

    const int gblocks = (N_NODES + 127) / 128;   // 391
    gemm_kernel<<<gblocks, 256, 0, stream>>>(featb, hneighb, Wf, bself, out);
}

// Round 12
// 133.255 us; speedup vs baseline: 2.9948x; 2.9948x over previous
//
#include <hip/hip_runtime.h>
#include <hip/hip_fp8.h>
#include <cstddef>
#include <cstdint>

#define N_NODES 50000
#define N_EDGES 800000
#define D 128
#define NWG 128                            // binning workgroups
#define EPW (N_EDGES / NWG)                // 6250 edges per wg
#define NBUCK 196                          // ceil(50000/256)
#define FCONV_BLKS 3125                    // N*D/8/256
#define WSPLIT_BLKS 16
#define SLICE_STRIDE (N_NODES * 16)        // elements per slice in hneighb_sliced

typedef __attribute__((ext_vector_type(8))) short bf16x8;
typedef __attribute__((ext_vector_type(16))) float f32x16;
typedef __attribute__((ext_vector_type(2))) float f32x2;

__device__ __forceinline__ unsigned short f32_to_bf16_rne(float x) {
    unsigned u = __builtin_bit_cast(unsigned, x);
    unsigned r = (u + 0x7FFFu + ((u >> 16) & 1u)) >> 16;
    return (unsigned short)r;
}

// ---- fp8 e4m3 pack/unpack (HW cvt on gfx950; hip_fp8 fallback) ----
#if __has_builtin(__builtin_amdgcn_cvt_pk_fp8_f32) && __has_builtin(__builtin_amdgcn_cvt_pk_f32_fp8)
__device__ __forceinline__ unsigned fp8x4_pack(float v0, float v1, float v2, float v3) {
    int w = 0;
    w = __builtin_amdgcn_cvt_pk_fp8_f32(v0, v1, w, false);   // bytes 0,1
    w = __builtin_amdgcn_cvt_pk_fp8_f32(v2, v3, w, true);    // bytes 2,3
    return (unsigned)w;
}
__device__ __forceinline__ f32x2 fp8x2_lo(unsigned u) {
    return __builtin_amdgcn_cvt_pk_f32_fp8((int)u, false);
}
__device__ __forceinline__ f32x2 fp8x2_hi(unsigned u) {
    return __builtin_amdgcn_cvt_pk_f32_fp8((int)u, true);
}
#else
__device__ __forceinline__ unsigned fp8x4_pack(float v0, float v1, float v2, float v3) {
    __hip_fp8_e4m3 a(v0), b(v1), c(v2), d(v3);
    return (unsigned)a.__x | ((unsigned)b.__x << 8) | ((unsigned)c.__x << 16) | ((unsigned)d.__x << 24);
}
__device__ __forceinline__ float fp8_dec(unsigned byte) {
    __hip_fp8_e4m3 h; h.__x = (__hip_fp8_storage_t)byte;
    return (float)h;
}
__device__ __forceinline__ f32x2 fp8x2_lo(unsigned u) {
    f32x2 r; r.x = fp8_dec(u & 255u); r.y = fp8_dec((u >> 8) & 255u); return r;
}
__device__ __forceinline__ f32x2 fp8x2_hi(unsigned u) {
    f32x2 r; r.x = fp8_dec((u >> 16) & 255u); r.y = fp8_dec(u >> 24); return r;
}
#endif

// ---------------- prep: fconv (bf16 + fp8 tables) | wsplit | s1 histogram ----------------
__launch_bounds__(256)
__global__ void prep_kernel(const float* __restrict__ feat,
                            const float* __restrict__ Wself,
                            const float* __restrict__ Wneigh,
                            const int* __restrict__ dst,
                            unsigned short* __restrict__ featb,
                            unsigned char* __restrict__ feat8,
                            unsigned short* __restrict__ Wf,
                            int* __restrict__ ghist) {
    __shared__ int hist[256];
    const int bid = blockIdx.x;
    const int t = threadIdx.x;
    if (bid < FCONV_BLKS) {
        const int i = bid * 256 + t;   // 8 floats per thread, exact coverage
        if (i >= N_NODES * D / 8) return;
        const float* gp = feat + (size_t)i * 8;
        const float4 a = *(const float4*)gp;
        const float4 b = *(const float4*)(gp + 4);
        bf16x8 h;
        h[0] = (short)f32_to_bf16_rne(a.x); h[1] = (short)f32_to_bf16_rne(a.y);
        h[2] = (short)f32_to_bf16_rne(a.z); h[3] = (short)f32_to_bf16_rne(a.w);
        h[4] = (short)f32_to_bf16_rne(b.x); h[5] = (short)f32_to_bf16_rne(b.y);
        h[6] = (short)f32_to_bf16_rne(b.z); h[7] = (short)f32_to_bf16_rne(b.w);
        *(bf16x8*)&featb[(size_t)i * 8] = h;
        uint2 q;
        q.x = fp8x4_pack(a.x, a.y, a.z, a.w);
        q.y = fp8x4_pack(b.x, b.y, b.z, b.w);
        *(uint2*)&feat8[(size_t)i * 8] = q;
    } else if (bid < FCONV_BLKS + WSPLIT_BLKS) {
        const int unit = (bid - FCONV_BLKS) * 256 + t;
        if (unit >= 4096) return;
        const int phase = unit >> 11;        // 0..1
        const int kbi   = (unit >> 9) & 3;   // 0..3
        const int u     = unit & 511;
        const int j     = u & 127;
        const int c     = u >> 7;            // 0..3
        const float* __restrict__ W = phase ? Wneigh : Wself;
        const float* gp = &W[(size_t)j * D + kbi * 32 + c * 8];
        const int p = j >> 5, ks = c >> 1, g = c & 1;
        const size_t base = (size_t)(phase * 4 + kbi) * 4096
                          + (size_t)(((p * 2 + ks) * 64) + (j & 31) + 32 * g) * 8;
#pragma unroll
        for (int e = 0; e < 8; ++e)
            Wf[base + e] = f32_to_bf16_rne(gp[e]);
    } else {
        const int w = bid - FCONV_BLKS - WSPLIT_BLKS;
        hist[t] = 0;
        __syncthreads();
        const int base = w * EPW;
        for (int i = t; i < EPW; i += 256)
            atomicAdd(&hist[dst[base + i] >> 8], 1);
        __syncthreads();
        ghist[w * 256 + t] = hist[t];
    }
}

// ---------------- S3 (with inline S2): scan ghist + bin edges packed ----------------
__launch_bounds__(256)
__global__ void s3_bin_kernel(const int* __restrict__ src,
                              const int* __restrict__ dst,
                              const int* __restrict__ ghist,
                              unsigned* __restrict__ binned,
                              int* __restrict__ gboff) {
    __shared__ int s[256];
    __shared__ int cur[256];
    const int t = threadIdx.x;
    const int w = blockIdx.x;
    int tot = 0, mypre = 0;
    for (int w2 = 0; w2 < NWG; ++w2) {
        const int v = ghist[w2 * 256 + t];
        tot += v;
        if (w2 < w) mypre += v;
    }
    s[t] = tot;
    __syncthreads();
    for (int d = 1; d < 256; d <<= 1) {
        int v = 0;
        if (t >= d) v = s[t - d];
        __syncthreads();
        s[t] += v;
        __syncthreads();
    }
    const int boff = s[t] - tot;   // exclusive bucket offset
    if (w == 0) {
        gboff[t] = boff;
        if (t == 255) gboff[256] = s[255];
    }
    cur[t] = boff + mypre;
    __syncthreads();
    const int base = w * EPW;
    for (int i = t; i < EPW; i += 256) {
        const int sv = src[base + i];
        const int d = dst[base + i];
        const int p = atomicAdd(&cur[d >> 8], 1);
        binned[p] = (unsigned)sv | ((unsigned)(d & 255) << 16);
    }
}

// ---------------- finalize: per-bucket degree + intra-bucket scan + CSR scatter ----------------
__launch_bounds__(256)
__global__ void finalize_kernel(const unsigned* __restrict__ binned,
                                const int* __restrict__ gboff,
                                int* __restrict__ deg_i,
                                int* __restrict__ off,
                                unsigned short* __restrict__ csr_src) {
    __shared__ int c0[256];
    __shared__ int s[256];
    __shared__ int cur[256];
    const int t = threadIdx.x;
    const int b = blockIdx.x;
    c0[t] = 0;
    __syncthreads();
    const int lo = gboff[b], hi = gboff[b + 1];
    for (int i = lo + t; i < hi; i += 256)
        atomicAdd(&c0[(binned[i] >> 16) & 255u], 1);
    __syncthreads();
    const int c = c0[t];
    s[t] = c;
    __syncthreads();
    for (int d = 1; d < 256; d <<= 1) {
        int v = 0;
        if (t >= d) v = s[t - d];
        __syncthreads();
        s[t] += v;
        __syncthreads();
    }
    const int o = gboff[b] + s[t] - c;   // global CSR offset for this node
    const int node = b * 256 + t;
    if (node < N_NODES) {
        deg_i[node] = c;
        off[node] = o;
    }
    cur[t] = o;
    __syncthreads();
    for (int i = lo + t; i < hi; i += 256) {
        const unsigned u = binned[i];
        const int p = atomicAdd(&cur[(u >> 16) & 255u], 1);
        csr_src[p] = (unsigned short)(u & 0xFFFFu);
    }
}

// ---------------- gather-aggregate: XCD feature-slice version ----------------
// slice = blockIdx & 7  (round-robin dispatch -> one slice per XCD -> 800 KB
// feat8 stripe is L2-resident). Thread = node; 16 feats (16 B fp8) per edge.
// Output slice-major: hneighb[slice][node][16] (coalesced 32 B per thread).
__launch_bounds__(256)
__global__ void gather_kernel(const unsigned char* __restrict__ feat8,
                              const int* __restrict__ off,
                              const int* __restrict__ deg_i,
                              const unsigned short* __restrict__ csr_src,
                              unsigned short* __restrict__ hneighb) {
    const int t = threadIdx.x;
    const int slice = blockIdx.x & 7;               // XCD-aligned feature slice
    const int nb    = blockIdx.x >> 3;              // node block 0..195
    const int node  = nb * 256 + t;
    if (node >= N_NODES) return;
    const int s0 = off[node];
    const int cnt = deg_i[node];
    const int end = s0 + cnt;
    const size_t fofs = (size_t)slice * 16;         // byte/feature offset in row

    float a[16];
#pragma unroll
    for (int k = 0; k < 16; ++k) a[k] = 0.f;

#define ACC(u) { const f32x2 p0 = fp8x2_lo((u).x); const f32x2 p1 = fp8x2_hi((u).x); \
                 const f32x2 p2 = fp8x2_lo((u).y); const f32x2 p3 = fp8x2_hi((u).y); \
                 const f32x2 p4 = fp8x2_lo((u).z); const f32x2 p5 = fp8x2_hi((u).z); \
                 const f32x2 p6 = fp8x2_lo((u).w); const f32x2 p7 = fp8x2_hi((u).w); \
                 a[0] += p0.x; a[1] += p0.y; a[2]  += p1.x; a[3]  += p1.y; \
                 a[4] += p2.x; a[5] += p2.y; a[6]  += p3.x; a[7]  += p3.y; \
                 a[8] += p4.x; a[9] += p4.y; a[10] += p5.x; a[11] += p5.y; \
                 a[12] += p6.x; a[13] += p6.y; a[14] += p7.x; a[15] += p7.y; }

    int e = s0;
    for (; e + 4 <= end; e += 4) {
        const int i0 = csr_src[e];
        const int i1 = csr_src[e + 1];
        const int i2 = csr_src[e + 2];
        const int i3 = csr_src[e + 3];
        const uint4 u0 = *(const uint4*)&feat8[(size_t)i0 * D + fofs];
        const uint4 u1 = *(const uint4*)&feat8[(size_t)i1 * D + fofs];
        const uint4 u2 = *(const uint4*)&feat8[(size_t)i2 * D + fofs];
        const uint4 u3 = *(const uint4*)&feat8[(size_t)i3 * D + fofs];
        ACC(u0); ACC(u1); ACC(u2); ACC(u3);
    }
    for (; e < end; ++e) {
        const uint4 u = *(const uint4*)&feat8[(size_t)csr_src[e] * D + fofs];
        ACC(u);
    }
#undef ACC

    const float sc = 1.f / fmaxf((float)cnt, 1.f);
    unsigned short* op = &hneighb[(size_t)slice * SLICE_STRIDE + (size_t)node * 16];
    bf16x8 o0, o1;
#pragma unroll
    for (int k = 0; k < 8; ++k) o0[k] = (short)f32_to_bf16_rne(a[k] * sc);
#pragma unroll
    for (int k = 0; k < 8; ++k) o1[k] = (short)f32_to_bf16_rne(a[8 + k] * sc);
    *(bf16x8*)op = o0;
    *(bf16x8*)(op + 8) = o1;
}

// ---------------- MFMA GEMM, pure bf16, W resident in LDS ----------------
__launch_bounds__(256)
__global__ void gemm_kernel(const unsigned short* __restrict__ featb,
                            const unsigned short* __restrict__ hneighb,
                            const unsigned short* __restrict__ Wf,
                            const float* __restrict__ bias,
                            float* __restrict__ out) {
    __shared__ __align__(16) unsigned short sW[32768];      // 64 KB: all 8 W chunks
    __shared__ __align__(16) unsigned short sA[2][4096];    // 2 x 8 KB A tiles

    const int tid  = threadIdx.x;
    const int wv   = tid >> 6;   // wave 0..3 -> A panel (rows wv*32..wv*32+31)
    const int l    = tid & 63;
    const int row0 = blockIdx.x * 128;

    // ---- load ALL of W once (64 KB, contiguous) ----
#pragma unroll
    for (int i = 0; i < 16; ++i) {
        const int o = (i * 256 + tid) * 8;
        *(bf16x8*)&sW[o] = *(const bf16x8*)&Wf[o];
    }

    auto stageA = [&](int sel, int blk) {
        const int kbi = blk & 3;
#pragma unroll
        for (int i = 0; i < 2; ++i) {
            const int u   = i * 256 + tid;   // 0..511 = 128 rows x 4 chunks
            const int row = u & 127;
            const int c   = u >> 7;          // 8-k chunk within the 32-k block
            const int grow = row0 + row;
            bf16x8 v = {};
            if (grow < N_NODES) {
                if (blk < 4) {
                    v = *(const bf16x8*)&featb[(size_t)grow * D + kbi * 32 + c * 8];
                } else {
                    const int slice = 2 * kbi + (c >> 1);
                    v = *(const bf16x8*)&hneighb[(size_t)slice * SLICE_STRIDE
                                                 + (size_t)grow * 16 + (c & 1) * 8];
                }
            }
            const int p = row >> 5, ks = c >> 1, g = c & 1;
            const int o = ((p * 2 + ks) * 64 + (row & 31) + 32 * g) * 8;
            *(bf16x8*)&sA[sel][o] = v;
        }
    };

    f32x16 acc[4] = {};

    stageA(0, 0);
    __syncthreads();
#pragma unroll 1
    for (int blk = 0; blk < 8; ++blk) {
        const int cur = blk & 1;
        if (blk < 7) stageA(cur ^ 1, blk + 1);
        const int wbase = blk * 4096;
#pragma unroll
        for (int ks = 0; ks < 2; ++ks) {
            const bf16x8 a = *(const bf16x8*)&sA[cur][((wv * 2 + ks) * 64 + l) * 8];
#pragma unroll
            for (int n = 0; n < 4; ++n) {
                const bf16x8 w = *(const bf16x8*)&sW[wbase + ((n * 2 + ks) * 64 + l) * 8];
                acc[n] = __builtin_amdgcn_mfma_f32_32x32x16_bf16(a, w, acc[n], 0, 0, 0);
            }
        }
        __syncthreads();
    }

    // ---- epilogue: C/D layout col=l&31, row=(r&3)+8*(r>>2)+4*(l>>5) ----
    const int col = l & 31;
    const int hi2 = l >> 5;
    float bv[4];
#pragma unroll
    for (int n = 0; n < 4; ++n) bv[n] = bias[n * 32 + col];
#pragma unroll
    for (int r = 0; r < 16; ++r) {
        const int rloc = (r & 3) + 8 * (r >> 2) + 4 * hi2;
        const int grow = row0 + wv * 32 + rloc;
        if (grow < N_NODES) {
#pragma unroll
            for (int n = 0; n < 4; ++n)
                out[(size_t)grow * D + n * 32 + col] = acc[n][r] + bv[n];
        }
    }
}

extern "C" void kernel_launch(void* const* d_in, const int* in_sizes, int n_in,
                              void* d_out, int out_size, void* d_ws, size_t ws_size,
                              hipStream_t stream) {
    const float* feat  = (const float*)d_in[0];
    const float* Wn    = (const float*)d_in[1];  // W_neigh
    const float* Wsf   = (const float*)d_in[2];  // W_self
    const float* bself = (const float*)d_in[3];
    const int*   src   = (const int*)d_in[4];
    const int*   dst   = (const int*)d_in[5];
    float* out = (float*)d_out;

    // workspace layout (all sections keep 16B alignment)
    unsigned short* featb   = (unsigned short*)d_ws;               // N*D bf16
    unsigned short* hneighb = featb + (size_t)N_NODES * D;         // 8 x N x 16 bf16 (slice-major)
    unsigned* binned = (unsigned*)(hneighb + (size_t)N_NODES * D); // E uint (packed)
    unsigned short* csr_src = (unsigned short*)(binned + N_EDGES); // E ushort
    int*   deg_i     = (int*)(csr_src + N_EDGES);                  // N ints
    int*   off       = deg_i + N_NODES;                            // N ints
    int*   ghist     = off + N_NODES;                              // NWG*256 ints
    int*   gboff     = ghist + NWG * 256;                          // 257 ints (pad 320)
    unsigned short* Wf = (unsigned short*)(gboff + 320);           // 8*4096 bf16
    unsigned char* feat8 = (unsigned char*)(Wf + 8 * 4096);        // N*D fp8

    prep_kernel<<<FCONV_BLKS + WSPLIT_BLKS + NWG, 256, 0, stream>>>(
        feat, Wsf, Wn, dst, featb, feat8, Wf, ghist);
    s3_bin_kernel<<<NWG, 256, 0, stream>>>(src, dst, ghist, binned, gboff);
    finalize_kernel<<<NBUCK, 256, 0, stream>>>(binned, gboff, deg_i, off, csr_src);
    gather_kernel<<<NBUCK * 8, 256, 0, stream>>>(feat8, off, deg_i, csr_src, hneighb);

    const int gblocks = (N_NODES + 127) / 128;   // 391
    gemm_kernel<<<gblocks, 256, 0, stream>>>(featb, hneighb, Wf, bself, out);
}

// Round 13
// 84.637 us; speedup vs baseline: 4.7152x; 1.5744x over previous
//
#include <hip/hip_runtime.h>
#include <hip/hip_fp8.h>
#include <cstddef>
#include <cstdint>

#define N_NODES 50000
#define N_EDGES 800000
#define D 128
#define NWG 128                            // binning workgroups
#define EPW (N_EDGES / NWG)                // 6250 edges per wg
#define NBUCK 196                          // ceil(50000/256)
#define FCONV_BLKS 3125                    // N*D/8/256
#define WSPLIT_BLKS 16
#define SLICE2 (N_NODES * 64)              // bf16 elems per 64-feature slice

typedef __attribute__((ext_vector_type(8))) short bf16x8;
typedef __attribute__((ext_vector_type(16))) float f32x16;
typedef __attribute__((ext_vector_type(2))) float f32x2;

__device__ __forceinline__ unsigned short f32_to_bf16_rne(float x) {
    unsigned u = __builtin_bit_cast(unsigned, x);
    unsigned r = (u + 0x7FFFu + ((u >> 16) & 1u)) >> 16;
    return (unsigned short)r;
}

// ---- fp8 e4m3 pack/unpack (HW cvt on gfx950; hip_fp8 fallback) ----
#if __has_builtin(__builtin_amdgcn_cvt_pk_fp8_f32) && __has_builtin(__builtin_amdgcn_cvt_pk_f32_fp8)
__device__ __forceinline__ unsigned fp8x4_pack(float v0, float v1, float v2, float v3) {
    int w = 0;
    w = __builtin_amdgcn_cvt_pk_fp8_f32(v0, v1, w, false);   // bytes 0,1
    w = __builtin_amdgcn_cvt_pk_fp8_f32(v2, v3, w, true);    // bytes 2,3
    return (unsigned)w;
}
__device__ __forceinline__ f32x2 fp8x2_lo(unsigned u) {
    return __builtin_amdgcn_cvt_pk_f32_fp8((int)u, false);
}
__device__ __forceinline__ f32x2 fp8x2_hi(unsigned u) {
    return __builtin_amdgcn_cvt_pk_f32_fp8((int)u, true);
}
#else
__device__ __forceinline__ unsigned fp8x4_pack(float v0, float v1, float v2, float v3) {
    __hip_fp8_e4m3 a(v0), b(v1), c(v2), d(v3);
    return (unsigned)a.__x | ((unsigned)b.__x << 8) | ((unsigned)c.__x << 16) | ((unsigned)d.__x << 24);
}
__device__ __forceinline__ float fp8_dec(unsigned byte) {
    __hip_fp8_e4m3 h; h.__x = (__hip_fp8_storage_t)byte;
    return (float)h;
}
__device__ __forceinline__ f32x2 fp8x2_lo(unsigned u) {
    f32x2 r; r.x = fp8_dec(u & 255u); r.y = fp8_dec((u >> 8) & 255u); return r;
}
__device__ __forceinline__ f32x2 fp8x2_hi(unsigned u) {
    f32x2 r; r.x = fp8_dec((u >> 16) & 255u); r.y = fp8_dec(u >> 24); return r;
}
#endif

// ---------------- prep: fconv (bf16 + fp8 tables) | wsplit | s1 histogram ----------------
__launch_bounds__(256)
__global__ void prep_kernel(const float* __restrict__ feat,
                            const float* __restrict__ Wself,
                            const float* __restrict__ Wneigh,
                            const int* __restrict__ dst,
                            unsigned short* __restrict__ featb,
                            unsigned char* __restrict__ feat8,
                            unsigned short* __restrict__ Wf,
                            int* __restrict__ ghist) {
    __shared__ int hist[256];
    const int bid = blockIdx.x;
    const int t = threadIdx.x;
    if (bid < FCONV_BLKS) {
        const int i = bid * 256 + t;   // 8 floats per thread, exact coverage
        if (i >= N_NODES * D / 8) return;
        const float* gp = feat + (size_t)i * 8;
        const float4 a = *(const float4*)gp;
        const float4 b = *(const float4*)(gp + 4);
        bf16x8 h;
        h[0] = (short)f32_to_bf16_rne(a.x); h[1] = (short)f32_to_bf16_rne(a.y);
        h[2] = (short)f32_to_bf16_rne(a.z); h[3] = (short)f32_to_bf16_rne(a.w);
        h[4] = (short)f32_to_bf16_rne(b.x); h[5] = (short)f32_to_bf16_rne(b.y);
        h[6] = (short)f32_to_bf16_rne(b.z); h[7] = (short)f32_to_bf16_rne(b.w);
        *(bf16x8*)&featb[(size_t)i * 8] = h;
        uint2 q;
        q.x = fp8x4_pack(a.x, a.y, a.z, a.w);
        q.y = fp8x4_pack(b.x, b.y, b.z, b.w);
        *(uint2*)&feat8[(size_t)i * 8] = q;
    } else if (bid < FCONV_BLKS + WSPLIT_BLKS) {
        const int unit = (bid - FCONV_BLKS) * 256 + t;
        if (unit >= 4096) return;
        const int phase = unit >> 11;        // 0..1
        const int kbi   = (unit >> 9) & 3;   // 0..3
        const int u     = unit & 511;
        const int j     = u & 127;
        const int c     = u >> 7;            // 0..3
        const float* __restrict__ W = phase ? Wneigh : Wself;
        const float* gp = &W[(size_t)j * D + kbi * 32 + c * 8];
        const int p = j >> 5, ks = c >> 1, g = c & 1;
        const size_t base = (size_t)(phase * 4 + kbi) * 4096
                          + (size_t)(((p * 2 + ks) * 64) + (j & 31) + 32 * g) * 8;
#pragma unroll
        for (int e = 0; e < 8; ++e)
            Wf[base + e] = f32_to_bf16_rne(gp[e]);
    } else {
        const int w = bid - FCONV_BLKS - WSPLIT_BLKS;
        hist[t] = 0;
        __syncthreads();
        const int base = w * EPW;
        for (int i = t; i < EPW; i += 256)
            atomicAdd(&hist[dst[base + i] >> 8], 1);
        __syncthreads();
        ghist[w * 256 + t] = hist[t];
    }
}

// ---------------- S3 (with inline S2): scan ghist + bin edges packed ----------------
__launch_bounds__(256)
__global__ void s3_bin_kernel(const int* __restrict__ src,
                              const int* __restrict__ dst,
                              const int* __restrict__ ghist,
                              unsigned* __restrict__ binned,
                              int* __restrict__ gboff) {
    __shared__ int s[256];
    __shared__ int cur[256];
    const int t = threadIdx.x;
    const int w = blockIdx.x;
    int tot = 0, mypre = 0;
    for (int w2 = 0; w2 < NWG; ++w2) {
        const int v = ghist[w2 * 256 + t];
        tot += v;
        if (w2 < w) mypre += v;
    }
    s[t] = tot;
    __syncthreads();
    for (int d = 1; d < 256; d <<= 1) {
        int v = 0;
        if (t >= d) v = s[t - d];
        __syncthreads();
        s[t] += v;
        __syncthreads();
    }
    const int boff = s[t] - tot;   // exclusive bucket offset
    if (w == 0) {
        gboff[t] = boff;
        if (t == 255) gboff[256] = s[255];
    }
    cur[t] = boff + mypre;
    __syncthreads();
    const int base = w * EPW;
    for (int i = t; i < EPW; i += 256) {
        const int sv = src[base + i];
        const int d = dst[base + i];
        const int p = atomicAdd(&cur[d >> 8], 1);
        binned[p] = (unsigned)sv | ((unsigned)(d & 255) << 16);
    }
}

// ---------------- finalize: per-bucket degree + intra-bucket scan + CSR scatter ----------------
__launch_bounds__(256)
__global__ void finalize_kernel(const unsigned* __restrict__ binned,
                                const int* __restrict__ gboff,
                                int* __restrict__ deg_i,
                                int* __restrict__ off,
                                unsigned short* __restrict__ csr_src) {
    __shared__ int c0[256];
    __shared__ int s[256];
    __shared__ int cur[256];
    const int t = threadIdx.x;
    const int b = blockIdx.x;
    c0[t] = 0;
    __syncthreads();
    const int lo = gboff[b], hi = gboff[b + 1];
    for (int i = lo + t; i < hi; i += 256)
        atomicAdd(&c0[(binned[i] >> 16) & 255u], 1);
    __syncthreads();
    const int c = c0[t];
    s[t] = c;
    __syncthreads();
    for (int d = 1; d < 256; d <<= 1) {
        int v = 0;
        if (t >= d) v = s[t - d];
        __syncthreads();
        s[t] += v;
        __syncthreads();
    }
    const int o = gboff[b] + s[t] - c;   // global CSR offset for this node
    const int node = b * 256 + t;
    if (node < N_NODES) {
        deg_i[node] = c;
        off[node] = o;
    }
    cur[t] = o;
    __syncthreads();
    for (int i = lo + t; i < hi; i += 256) {
        const unsigned u = binned[i];
        const int p = atomicAdd(&cur[(u >> 16) & 255u], 1);
        csr_src[p] = (unsigned short)(u & 0xFFFFu);
    }
}

// ---------------- gather-aggregate: 2 slices x 64B (line-aligned), XCD-affine ----------------
// slice = blockIdx & 1 (round-robin XCDs -> even XCDs slice 0, odd slice 1).
// Per-XCD feat8 footprint: 50000 x 64B full lines = 3.2 MB < 4 MB L2.
// 8 lanes/row x uint2(8B); 32 nodes/block; unroll 8 -> 8 outstanding loads/thread.
__launch_bounds__(256)
__global__ void gather_kernel(const unsigned char* __restrict__ feat8,
                              const int* __restrict__ off,
                              const int* __restrict__ deg_i,
                              const unsigned short* __restrict__ csr_src,
                              unsigned short* __restrict__ hneighb) {
    const int t = threadIdx.x;
    const int slice = blockIdx.x & 1;
    const int node  = (blockIdx.x >> 1) * 32 + (t >> 3);
    const int l3    = t & 7;                       // lane within row-group
    if (node >= N_NODES) return;
    const int s0 = off[node];
    const int cnt = deg_i[node];
    const int end = s0 + cnt;
    const size_t fofs = (size_t)slice * 64 + l3 * 8;   // byte offset in fp8 row

    float a0 = 0.f, a1 = 0.f, a2 = 0.f, a3 = 0.f;
    float a4 = 0.f, a5 = 0.f, a6 = 0.f, a7 = 0.f;
    int e = s0;
#define ACC(u) { const f32x2 p0 = fp8x2_lo((u).x); const f32x2 p1 = fp8x2_hi((u).x); \
                 const f32x2 p2 = fp8x2_lo((u).y); const f32x2 p3 = fp8x2_hi((u).y); \
                 a0 += p0.x; a1 += p0.y; a2 += p1.x; a3 += p1.y; \
                 a4 += p2.x; a5 += p2.y; a6 += p3.x; a7 += p3.y; }
    for (; e + 8 <= end; e += 8) {
        const int i0 = csr_src[e];
        const int i1 = csr_src[e + 1];
        const int i2 = csr_src[e + 2];
        const int i3 = csr_src[e + 3];
        const int i4 = csr_src[e + 4];
        const int i5 = csr_src[e + 5];
        const int i6 = csr_src[e + 6];
        const int i7 = csr_src[e + 7];
        const uint2 u0 = *(const uint2*)&feat8[(size_t)i0 * D + fofs];
        const uint2 u1 = *(const uint2*)&feat8[(size_t)i1 * D + fofs];
        const uint2 u2 = *(const uint2*)&feat8[(size_t)i2 * D + fofs];
        const uint2 u3 = *(const uint2*)&feat8[(size_t)i3 * D + fofs];
        const uint2 u4 = *(const uint2*)&feat8[(size_t)i4 * D + fofs];
        const uint2 u5 = *(const uint2*)&feat8[(size_t)i5 * D + fofs];
        const uint2 u6 = *(const uint2*)&feat8[(size_t)i6 * D + fofs];
        const uint2 u7 = *(const uint2*)&feat8[(size_t)i7 * D + fofs];
        ACC(u0); ACC(u1); ACC(u2); ACC(u3);
        ACC(u4); ACC(u5); ACC(u6); ACC(u7);
    }
    for (; e + 4 <= end; e += 4) {
        const int i0 = csr_src[e];
        const int i1 = csr_src[e + 1];
        const int i2 = csr_src[e + 2];
        const int i3 = csr_src[e + 3];
        const uint2 u0 = *(const uint2*)&feat8[(size_t)i0 * D + fofs];
        const uint2 u1 = *(const uint2*)&feat8[(size_t)i1 * D + fofs];
        const uint2 u2 = *(const uint2*)&feat8[(size_t)i2 * D + fofs];
        const uint2 u3 = *(const uint2*)&feat8[(size_t)i3 * D + fofs];
        ACC(u0); ACC(u1); ACC(u2); ACC(u3);
    }
    for (; e < end; ++e) {
        const uint2 u = *(const uint2*)&feat8[(size_t)csr_src[e] * D + fofs];
        ACC(u);
    }
#undef ACC
    const float sc = 1.f / fmaxf((float)cnt, 1.f);
    bf16x8 o;
    o[0] = (short)f32_to_bf16_rne(a0 * sc);
    o[1] = (short)f32_to_bf16_rne(a1 * sc);
    o[2] = (short)f32_to_bf16_rne(a2 * sc);
    o[3] = (short)f32_to_bf16_rne(a3 * sc);
    o[4] = (short)f32_to_bf16_rne(a4 * sc);
    o[5] = (short)f32_to_bf16_rne(a5 * sc);
    o[6] = (short)f32_to_bf16_rne(a6 * sc);
    o[7] = (short)f32_to_bf16_rne(a7 * sc);
    // slice-major: hneighb[slice][node][64]
    *(bf16x8*)&hneighb[(size_t)slice * SLICE2 + (size_t)node * 64 + l3 * 8] = o;
}

// ---------------- MFMA GEMM, pure bf16, W resident in LDS ----------------
__launch_bounds__(256)
__global__ void gemm_kernel(const unsigned short* __restrict__ featb,
                            const unsigned short* __restrict__ hneighb,
                            const unsigned short* __restrict__ Wf,
                            const float* __restrict__ bias,
                            float* __restrict__ out) {
    __shared__ __align__(16) unsigned short sW[32768];      // 64 KB: all 8 W chunks
    __shared__ __align__(16) unsigned short sA[2][4096];    // 2 x 8 KB A tiles

    const int tid  = threadIdx.x;
    const int wv   = tid >> 6;   // wave 0..3 -> A panel (rows wv*32..wv*32+31)
    const int l    = tid & 63;
    const int row0 = blockIdx.x * 128;

    // ---- load ALL of W once (64 KB, contiguous) ----
#pragma unroll
    for (int i = 0; i < 16; ++i) {
        const int o = (i * 256 + tid) * 8;
        *(bf16x8*)&sW[o] = *(const bf16x8*)&Wf[o];
    }

    auto stageA = [&](int sel, int blk) {
        const int kbi = blk & 3;
#pragma unroll
        for (int i = 0; i < 2; ++i) {
            const int u   = i * 256 + tid;   // 0..511 = 128 rows x 4 chunks
            const int row = u & 127;
            const int c   = u >> 7;          // 8-k chunk within the 32-k block
            const int grow = row0 + row;
            bf16x8 v = {};
            if (grow < N_NODES) {
                if (blk < 4) {
                    v = *(const bf16x8*)&featb[(size_t)grow * D + kbi * 32 + c * 8];
                } else {
                    // feature f = kbi*32 + c*8; slice = kbi>>1; in-slice = (kbi&1)*32 + c*8
                    v = *(const bf16x8*)&hneighb[(size_t)(kbi >> 1) * SLICE2
                                                 + (size_t)grow * 64 + (kbi & 1) * 32 + c * 8];
                }
            }
            const int p = row >> 5, ks = c >> 1, g = c & 1;
            const int o = ((p * 2 + ks) * 64 + (row & 31) + 32 * g) * 8;
            *(bf16x8*)&sA[sel][o] = v;
        }
    };

    f32x16 acc[4] = {};

    stageA(0, 0);
    __syncthreads();
#pragma unroll 1
    for (int blk = 0; blk < 8; ++blk) {
        const int cur = blk & 1;
        if (blk < 7) stageA(cur ^ 1, blk + 1);
        const int wbase = blk * 4096;
#pragma unroll
        for (int ks = 0; ks < 2; ++ks) {
            const bf16x8 a = *(const bf16x8*)&sA[cur][((wv * 2 + ks) * 64 + l) * 8];
#pragma unroll
            for (int n = 0; n < 4; ++n) {
                const bf16x8 w = *(const bf16x8*)&sW[wbase + ((n * 2 + ks) * 64 + l) * 8];
                acc[n] = __builtin_amdgcn_mfma_f32_32x32x16_bf16(a, w, acc[n], 0, 0, 0);
            }
        }
        __syncthreads();
    }

    // ---- epilogue: C/D layout col=l&31, row=(r&3)+8*(r>>2)+4*(l>>5) ----
    const int col = l & 31;
    const int hi2 = l >> 5;
    float bv[4];
#pragma unroll
    for (int n = 0; n < 4; ++n) bv[n] = bias[n * 32 + col];
#pragma unroll
    for (int r = 0; r < 16; ++r) {
        const int rloc = (r & 3) + 8 * (r >> 2) + 4 * hi2;
        const int grow = row0 + wv * 32 + rloc;
        if (grow < N_NODES) {
#pragma unroll
            for (int n = 0; n < 4; ++n)
                out[(size_t)grow * D + n * 32 + col] = acc[n][r] + bv[n];
        }
    }
}

extern "C" void kernel_launch(void* const* d_in, const int* in_sizes, int n_in,
                              void* d_out, int out_size, void* d_ws, size_t ws_size,
                              hipStream_t stream) {
    const float* feat  = (const float*)d_in[0];
    const float* Wn    = (const float*)d_in[1];  // W_neigh
    const float* Wsf   = (const float*)d_in[2];  // W_self
    const float* bself = (const float*)d_in[3];
    const int*   src   = (const int*)d_in[4];
    const int*   dst   = (const int*)d_in[5];
    float* out = (float*)d_out;

    // workspace layout (all sections keep 16B alignment)
    unsigned short* featb   = (unsigned short*)d_ws;               // N*D bf16
    unsigned short* hneighb = featb + (size_t)N_NODES * D;         // 2 x N x 64 bf16 (slice-major)
    unsigned* binned = (unsigned*)(hneighb + (size_t)N_NODES * D); // E uint (packed)
    unsigned short* csr_src = (unsigned short*)(binned + N_EDGES); // E ushort
    int*   deg_i     = (int*)(csr_src + N_EDGES);                  // N ints
    int*   off       = deg_i + N_NODES;                            // N ints
    int*   ghist     = off + N_NODES;                              // NWG*256 ints
    int*   gboff     = ghist + NWG * 256;                          // 257 ints (pad 320)
    unsigned short* Wf = (unsigned short*)(gboff + 320);           // 8*4096 bf16
    unsigned char* feat8 = (unsigned char*)(Wf + 8 * 4096);        // N*D fp8

    prep_kernel<<<FCONV_BLKS + WSPLIT_BLKS + NWG, 256, 0, stream>>>(
        feat, Wsf, Wn, dst, featb, feat8, Wf, ghist);
    s3_bin_kernel<<<NWG, 256, 0, stream>>>(src, dst, ghist, binned, gboff);
    finalize_kernel<<<NBUCK, 256, 0, stream>>>(binned, gboff, deg_i, off, csr_src);

    const int gb = 2 * ((N_NODES + 31) / 32);   // 3126: slice = bid&1
    gather_kernel<<<gb, 256, 0, stream>>>(feat8, off, deg_i, csr_src, hneighb);

    const int gblocks = (N_NODES + 127) / 128;   // 391
    gemm_kernel<<<gblocks, 256, 0, stream>>>(featb, hneighb, Wf, bself, out);
}

// Round 14
// 80.710 us; speedup vs baseline: 4.9446x; 1.0487x over previous
//
#include <hip/hip_runtime.h>
#include <hip/hip_fp8.h>
#include <cstddef>
#include <cstdint>

#define N_NODES 50000
#define N_EDGES 800000
#define D 128
#define NWG 128                            // binning workgroups
#define EPW (N_EDGES / NWG)                // 6250 edges per wg
#define NBUCK 196                          // ceil(50000/256)
#define FCONV_BLKS 3125                    // N*D/8/256
#define WSPLIT_BLKS 16
#define FIN_CAP 6144                       // finalize LDS cache entries (bucket avg 4082)

typedef __attribute__((ext_vector_type(8))) short bf16x8;
typedef __attribute__((ext_vector_type(16))) float f32x16;
typedef __attribute__((ext_vector_type(2))) float f32x2;

__device__ __forceinline__ unsigned short f32_to_bf16_rne(float x) {
    unsigned u = __builtin_bit_cast(unsigned, x);
    unsigned r = (u + 0x7FFFu + ((u >> 16) & 1u)) >> 16;
    return (unsigned short)r;
}

// ---- fp8 e4m3 pack/unpack (HW cvt on gfx950; hip_fp8 fallback) ----
#if __has_builtin(__builtin_amdgcn_cvt_pk_fp8_f32) && __has_builtin(__builtin_amdgcn_cvt_pk_f32_fp8)
__device__ __forceinline__ unsigned fp8x4_pack(float v0, float v1, float v2, float v3) {
    int w = 0;
    w = __builtin_amdgcn_cvt_pk_fp8_f32(v0, v1, w, false);   // bytes 0,1
    w = __builtin_amdgcn_cvt_pk_fp8_f32(v2, v3, w, true);    // bytes 2,3
    return (unsigned)w;
}
__device__ __forceinline__ f32x2 fp8x2_lo(unsigned u) {
    return __builtin_amdgcn_cvt_pk_f32_fp8((int)u, false);
}
__device__ __forceinline__ f32x2 fp8x2_hi(unsigned u) {
    return __builtin_amdgcn_cvt_pk_f32_fp8((int)u, true);
}
#else
__device__ __forceinline__ unsigned fp8x4_pack(float v0, float v1, float v2, float v3) {
    __hip_fp8_e4m3 a(v0), b(v1), c(v2), d(v3);
    return (unsigned)a.__x | ((unsigned)b.__x << 8) | ((unsigned)c.__x << 16) | ((unsigned)d.__x << 24);
}
__device__ __forceinline__ float fp8_dec(unsigned byte) {
    __hip_fp8_e4m3 h; h.__x = (__hip_fp8_storage_t)byte;
    return (float)h;
}
__device__ __forceinline__ f32x2 fp8x2_lo(unsigned u) {
    f32x2 r; r.x = fp8_dec(u & 255u); r.y = fp8_dec((u >> 8) & 255u); return r;
}
__device__ __forceinline__ f32x2 fp8x2_hi(unsigned u) {
    f32x2 r; r.x = fp8_dec((u >> 16) & 255u); r.y = fp8_dec(u >> 24); return r;
}
#endif

// ---------------- prep: fconv (bf16 + fp8 tables) | wsplit | s1 histogram ----------------
__launch_bounds__(256)
__global__ void prep_kernel(const float* __restrict__ feat,
                            const float* __restrict__ Wself,
                            const float* __restrict__ Wneigh,
                            const int* __restrict__ dst,
                            unsigned short* __restrict__ featb,
                            unsigned char* __restrict__ feat8,
                            unsigned short* __restrict__ Wf,
                            int* __restrict__ ghist) {
    __shared__ int hist[256];
    const int bid = blockIdx.x;
    const int t = threadIdx.x;
    if (bid < FCONV_BLKS) {
        const int i = bid * 256 + t;   // 8 floats per thread, exact coverage
        if (i >= N_NODES * D / 8) return;
        const float* gp = feat + (size_t)i * 8;
        const float4 a = *(const float4*)gp;
        const float4 b = *(const float4*)(gp + 4);
        bf16x8 h;
        h[0] = (short)f32_to_bf16_rne(a.x); h[1] = (short)f32_to_bf16_rne(a.y);
        h[2] = (short)f32_to_bf16_rne(a.z); h[3] = (short)f32_to_bf16_rne(a.w);
        h[4] = (short)f32_to_bf16_rne(b.x); h[5] = (short)f32_to_bf16_rne(b.y);
        h[6] = (short)f32_to_bf16_rne(b.z); h[7] = (short)f32_to_bf16_rne(b.w);
        *(bf16x8*)&featb[(size_t)i * 8] = h;
        uint2 q;
        q.x = fp8x4_pack(a.x, a.y, a.z, a.w);
        q.y = fp8x4_pack(b.x, b.y, b.z, b.w);
        *(uint2*)&feat8[(size_t)i * 8] = q;
    } else if (bid < FCONV_BLKS + WSPLIT_BLKS) {
        const int unit = (bid - FCONV_BLKS) * 256 + t;
        if (unit >= 4096) return;
        const int phase = unit >> 11;        // 0..1
        const int kbi   = (unit >> 9) & 3;   // 0..3
        const int u     = unit & 511;
        const int j     = u & 127;
        const int c     = u >> 7;            // 0..3
        const float* __restrict__ W = phase ? Wneigh : Wself;
        const float* gp = &W[(size_t)j * D + kbi * 32 + c * 8];
        const int p = j >> 5, ks = c >> 1, g = c & 1;
        const size_t base = (size_t)(phase * 4 + kbi) * 4096
                          + (size_t)(((p * 2 + ks) * 64) + (j & 31) + 32 * g) * 8;
#pragma unroll
        for (int e = 0; e < 8; ++e)
            Wf[base + e] = f32_to_bf16_rne(gp[e]);
    } else {
        const int w = bid - FCONV_BLKS - WSPLIT_BLKS;
        hist[t] = 0;
        __syncthreads();
        const int base = w * EPW;
        for (int i = t; i < EPW; i += 256)
            atomicAdd(&hist[dst[base + i] >> 8], 1);
        __syncthreads();
        ghist[w * 256 + t] = hist[t];
    }
}

// ---------------- S3 (with inline S2): scan ghist + bin edges packed ----------------
__launch_bounds__(256)
__global__ void s3_bin_kernel(const int* __restrict__ src,
                              const int* __restrict__ dst,
                              const int* __restrict__ ghist,
                              unsigned* __restrict__ binned,
                              int* __restrict__ gboff) {
    __shared__ int s[256];
    __shared__ int cur[256];
    const int t = threadIdx.x;
    const int w = blockIdx.x;
    int tot = 0, mypre = 0;
    for (int w2 = 0; w2 < NWG; ++w2) {
        const int v = ghist[w2 * 256 + t];
        tot += v;
        if (w2 < w) mypre += v;
    }
    s[t] = tot;
    __syncthreads();
    for (int d = 1; d < 256; d <<= 1) {
        int v = 0;
        if (t >= d) v = s[t - d];
        __syncthreads();
        s[t] += v;
        __syncthreads();
    }
    const int boff = s[t] - tot;   // exclusive bucket offset
    if (w == 0) {
        gboff[t] = boff;
        if (t == 255) gboff[256] = s[255];
    }
    cur[t] = boff + mypre;
    __syncthreads();
    const int base = w * EPW;
    for (int i = t; i < EPW; i += 256) {
        const int sv = src[base + i];
        const int d = dst[base + i];
        const int p = atomicAdd(&cur[d >> 8], 1);
        binned[p] = (unsigned)sv | ((unsigned)(d & 255) << 16);
    }
}

// ---------------- finalize: LDS-cached bucket, degree + scan + CSR scatter ----------------
__launch_bounds__(256)
__global__ void finalize_kernel(const unsigned* __restrict__ binned,
                                const int* __restrict__ gboff,
                                int* __restrict__ deg_i,
                                int* __restrict__ off,
                                unsigned short* __restrict__ csr_src) {
    __shared__ int c0[256];
    __shared__ int s[256];
    __shared__ int cur[256];
    __shared__ unsigned bcache[FIN_CAP];
    const int t = threadIdx.x;
    const int b = blockIdx.x;
    c0[t] = 0;
    __syncthreads();
    const int lo = gboff[b], hi = gboff[b + 1];
    const int n = hi - lo;
    const bool fits = (n <= FIN_CAP);
    for (int i = t; i < n; i += 256) {
        const unsigned u = binned[lo + i];
        if (fits) bcache[i] = u;
        atomicAdd(&c0[(u >> 16) & 255u], 1);
    }
    __syncthreads();
    const int c = c0[t];
    s[t] = c;
    __syncthreads();
    for (int d = 1; d < 256; d <<= 1) {
        int v = 0;
        if (t >= d) v = s[t - d];
        __syncthreads();
        s[t] += v;
        __syncthreads();
    }
    const int o = gboff[b] + s[t] - c;   // global CSR offset for this node
    const int node = b * 256 + t;
    if (node < N_NODES) {
        deg_i[node] = c;
        off[node] = o;
    }
    cur[t] = o;
    __syncthreads();
    for (int i = t; i < n; i += 256) {
        const unsigned u = fits ? bcache[i] : binned[lo + i];
        const int p = atomicAdd(&cur[(u >> 16) & 255u], 1);
        csr_src[p] = (unsigned short)(u & 0xFFFFu);
    }
}

// ---------------- gather-aggregate: fp8 rows, 8 lanes x uint4, 32 nodes/block ----------------
__launch_bounds__(256)
__global__ void gather_kernel(const unsigned char* __restrict__ feat8,
                              const int* __restrict__ off,
                              const int* __restrict__ deg_i,
                              const unsigned short* __restrict__ csr_src,
                              unsigned short* __restrict__ hneighb) {
    const int t = threadIdx.x;
    const int l = t & 7;                            // lane within row-group
    const size_t fofs = (size_t)l * 16;             // 16 fp8 bytes per lane
    const int node = blockIdx.x * 32 + (t >> 3);    // 32 nodes per 256-thread block
    if (node >= N_NODES) return;
    const int s0 = off[node];
    const int cnt = deg_i[node];
    const int end = s0 + cnt;

    float a[16];
#pragma unroll
    for (int k = 0; k < 16; ++k) a[k] = 0.f;

#define ACC(u) { const f32x2 p0 = fp8x2_lo((u).x); const f32x2 p1 = fp8x2_hi((u).x); \
                 const f32x2 p2 = fp8x2_lo((u).y); const f32x2 p3 = fp8x2_hi((u).y); \
                 const f32x2 p4 = fp8x2_lo((u).z); const f32x2 p5 = fp8x2_hi((u).z); \
                 const f32x2 p6 = fp8x2_lo((u).w); const f32x2 p7 = fp8x2_hi((u).w); \
                 a[0] += p0.x; a[1] += p0.y; a[2]  += p1.x; a[3]  += p1.y; \
                 a[4] += p2.x; a[5] += p2.y; a[6]  += p3.x; a[7]  += p3.y; \
                 a[8] += p4.x; a[9] += p4.y; a[10] += p5.x; a[11] += p5.y; \
                 a[12] += p6.x; a[13] += p6.y; a[14] += p7.x; a[15] += p7.y; }

    int e = s0;
    for (; e + 4 <= end; e += 4) {
        const int i0 = csr_src[e];
        const int i1 = csr_src[e + 1];
        const int i2 = csr_src[e + 2];
        const int i3 = csr_src[e + 3];
        const uint4 u0 = *(const uint4*)&feat8[(size_t)i0 * D + fofs];
        const uint4 u1 = *(const uint4*)&feat8[(size_t)i1 * D + fofs];
        const uint4 u2 = *(const uint4*)&feat8[(size_t)i2 * D + fofs];
        const uint4 u3 = *(const uint4*)&feat8[(size_t)i3 * D + fofs];
        ACC(u0); ACC(u1); ACC(u2); ACC(u3);
    }
    for (; e < end; ++e) {
        const uint4 u = *(const uint4*)&feat8[(size_t)csr_src[e] * D + fofs];
        ACC(u);
    }
#undef ACC

    const float sc = 1.f / fmaxf((float)cnt, 1.f);
    bf16x8 o0, o1;
#pragma unroll
    for (int k = 0; k < 8; ++k) o0[k] = (short)f32_to_bf16_rne(a[k] * sc);
#pragma unroll
    for (int k = 0; k < 8; ++k) o1[k] = (short)f32_to_bf16_rne(a[8 + k] * sc);
    unsigned short* op = &hneighb[(size_t)node * D + l * 16];
    *(bf16x8*)op = o0;
    *(bf16x8*)(op + 8) = o1;
}

// ---------------- MFMA GEMM, pure bf16, W resident in LDS ----------------
__launch_bounds__(256)
__global__ void gemm_kernel(const unsigned short* __restrict__ featb,
                            const unsigned short* __restrict__ hneighb,
                            const unsigned short* __restrict__ Wf,
                            const float* __restrict__ bias,
                            float* __restrict__ out) {
    __shared__ __align__(16) unsigned short sW[32768];      // 64 KB: all 8 W chunks
    __shared__ __align__(16) unsigned short sA[2][4096];    // 2 x 8 KB A tiles

    const int tid  = threadIdx.x;
    const int wv   = tid >> 6;   // wave 0..3 -> A panel (rows wv*32..wv*32+31)
    const int l    = tid & 63;
    const int row0 = blockIdx.x * 128;

    // ---- load ALL of W once (64 KB, contiguous) ----
#pragma unroll
    for (int i = 0; i < 16; ++i) {
        const int o = (i * 256 + tid) * 8;
        *(bf16x8*)&sW[o] = *(const bf16x8*)&Wf[o];
    }

    auto stageA = [&](int sel, int blk) {
        const int kbi = blk & 3;
        const unsigned short* __restrict__ A = (blk < 4) ? featb : hneighb;
#pragma unroll
        for (int i = 0; i < 2; ++i) {
            const int u   = i * 256 + tid;   // 0..511 = 128 rows x 4 chunks
            const int row = u & 127;
            const int c   = u >> 7;          // 8-k chunk within the 32-k block
            const int grow = row0 + row;
            bf16x8 v = {};
            if (grow < N_NODES)
                v = *(const bf16x8*)&A[(size_t)grow * D + kbi * 32 + c * 8];
            const int p = row >> 5, ks = c >> 1, g = c & 1;
            const int o = ((p * 2 + ks) * 64 + (row & 31) + 32 * g) * 8;
            *(bf16x8*)&sA[sel][o] = v;
        }
    };

    f32x16 acc[4] = {};

    stageA(0, 0);
    __syncthreads();
#pragma unroll 1
    for (int blk = 0; blk < 8; ++blk) {
        const int cur = blk & 1;
        if (blk < 7) stageA(cur ^ 1, blk + 1);
        const int wbase = blk * 4096;
#pragma unroll
        for (int ks = 0; ks < 2; ++ks) {
            const bf16x8 a = *(const bf16x8*)&sA[cur][((wv * 2 + ks) * 64 + l) * 8];
#pragma unroll
            for (int n = 0; n < 4; ++n) {
                const bf16x8 w = *(const bf16x8*)&sW[wbase + ((n * 2 + ks) * 64 + l) * 8];
                acc[n] = __builtin_amdgcn_mfma_f32_32x32x16_bf16(a, w, acc[n], 0, 0, 0);
            }
        }
        __syncthreads();
    }

    // ---- epilogue: C/D layout col=l&31, row=(r&3)+8*(r>>2)+4*(l>>5) ----
    const int col = l & 31;
    const int hi2 = l >> 5;
    float bv[4];
#pragma unroll
    for (int n = 0; n < 4; ++n) bv[n] = bias[n * 32 + col];
#pragma unroll
    for (int r = 0; r < 16; ++r) {
        const int rloc = (r & 3) + 8 * (r >> 2) + 4 * hi2;
        const int grow = row0 + wv * 32 + rloc;
        if (grow < N_NODES) {
#pragma unroll
            for (int n = 0; n < 4; ++n)
                out[(size_t)grow * D + n * 32 + col] = acc[n][r] + bv[n];
        }
    }
}

extern "C" void kernel_launch(void* const* d_in, const int* in_sizes, int n_in,
                              void* d_out, int out_size, void* d_ws, size_t ws_size,
                              hipStream_t stream) {
    const float* feat  = (const float*)d_in[0];
    const float* Wn    = (const float*)d_in[1];  // W_neigh
    const float* Wsf   = (const float*)d_in[2];  // W_self
    const float* bself = (const float*)d_in[3];
    const int*   src   = (const int*)d_in[4];
    const int*   dst   = (const int*)d_in[5];
    float* out = (float*)d_out;

    // workspace layout (all sections keep 16B alignment)
    unsigned short* featb   = (unsigned short*)d_ws;               // N*D bf16
    unsigned short* hneighb = featb + (size_t)N_NODES * D;         // N*D bf16
    unsigned* binned = (unsigned*)(hneighb + (size_t)N_NODES * D); // E uint (packed)
    unsigned short* csr_src = (unsigned short*)(binned + N_EDGES); // E ushort
    int*   deg_i     = (int*)(csr_src + N_EDGES);                  // N ints
    int*   off       = deg_i + N_NODES;                            // N ints
    int*   ghist     = off + N_NODES;                              // NWG*256 ints
    int*   gboff     = ghist + NWG * 256;                          // 257 ints (pad 320)
    unsigned short* Wf = (unsigned short*)(gboff + 320);           // 8*4096 bf16
    unsigned char* feat8 = (unsigned char*)(Wf + 8 * 4096);        // N*D fp8

    prep_kernel<<<FCONV_BLKS + WSPLIT_BLKS + NWG, 256, 0, stream>>>(
        feat, Wsf, Wn, dst, featb, feat8, Wf, ghist);
    s3_bin_kernel<<<NWG, 256, 0, stream>>>(src, dst, ghist, binned, gboff);
    finalize_kernel<<<NBUCK, 256, 0, stream>>>(binned, gboff, deg_i, off, csr_src);
    gather_kernel<<<(N_NODES + 31) / 32, 256, 0, stream>>>(feat8, off, deg_i, csr_src, hneighb);

    const int gblocks = (N_NODES + 127) / 128;   // 391
    gemm_kernel<<<gblocks, 256, 0, stream>>>(featb, hneighb, Wf, bself, out);
}